// Round 1
// baseline (877.633 us; speedup 1.0000x reference)
//
#include <hip/hip_runtime.h>
#include <hip/hip_bf16.h>
#include <cstdint>
#include <cstddef>
#include <math.h>

// GraphUNet forward on MI355X.
// Design: integer adjacencies computed exactly via bf16-MFMA (split planes),
// GCN matmuls via 3-way-split bf16 MFMA (fp32-faithful), fused augment+pool,
// deterministic K-split reduction, single-block bitonic top-k (stable ties).

#define DIVUP(a,b) (((a)+(b)-1)/(b))

using s16x8 = __attribute__((ext_vector_type(8))) short;
using f32x4 = __attribute__((ext_vector_type(4))) float;

__device__ __forceinline__ unsigned short f2bf(float v) {
    union { float f; unsigned u; } a; a.f = v;
    unsigned u = a.u;
    u = u + 0x7FFFu + ((u >> 16) & 1u);   // RNE
    return (unsigned short)(u >> 16);
}
__device__ __forceinline__ float bf2f(unsigned short h) {
    union { unsigned u; float f; } a; a.u = ((unsigned)h) << 16; return a.f;
}

// ---------------- small kernels ----------------

__global__ void k_scatter(const int* __restrict__ e, float* __restrict__ A, int E, int n) {
    int t = blockIdx.x * blockDim.x + threadIdx.x;
    if (t < E) atomicAdd(&A[(size_t)e[t] * n + e[E + t]], 1.0f);  // integer adds: deterministic
}

__global__ void k_a0_plane(const float* __restrict__ A, unsigned short* __restrict__ H,
                           float* __restrict__ d0, int n) {
    size_t t = (size_t)blockIdx.x * blockDim.x + threadIdx.x;
    if (t >= (size_t)n * n) return;
    int i = (int)(t / n), j = (int)(t % n);
    float v = A[t];
    if (i == j) { d0[i] = v; v = 1.0f; }   // planes store diag=1 (augment-ready)
    H[t] = f2bf(v);
}

__global__ void k_transpose_bf(const unsigned short* __restrict__ S, unsigned short* __restrict__ D, int n) {
    __shared__ unsigned short tile[32][33];
    int bx = blockIdx.x * 32, by = blockIdx.y * 32;
    #pragma unroll
    for (int dy = 0; dy < 32; dy += 8)
        tile[threadIdx.y + dy][threadIdx.x] = S[(size_t)(by + threadIdx.y + dy) * n + bx + threadIdx.x];
    __syncthreads();
    #pragma unroll
    for (int dy = 0; dy < 32; dy += 8)
        D[(size_t)(bx + threadIdx.y + dy) * n + by + threadIdx.x] = tile[threadIdx.x][threadIdx.y + dy];
}

// deg_i = rowsum(plane parts) - 1 (stored diag) + diag_true + 2 ; dis = rsqrt
__global__ void k_dis(const unsigned short* __restrict__ P0, const unsigned short* __restrict__ P1,
                      const unsigned short* __restrict__ P2, int nplanes,
                      const float* __restrict__ diagv, float* __restrict__ dis, int np) {
    int i = blockIdx.x;
    float s = 0.f;
    const unsigned short* pls[3] = {P0, P1, P2};
    for (int p = 0; p < nplanes; ++p) {
        const unsigned short* row = pls[p] + (size_t)i * np;
        for (int j = threadIdx.x; j < np; j += 256) s += bf2f(row[j]);
    }
    __shared__ float red[256];
    red[threadIdx.x] = s; __syncthreads();
    for (int o = 128; o > 0; o >>= 1) {
        if (threadIdx.x < o) red[threadIdx.x] += red[threadIdx.x + o];
        __syncthreads();
    }
    if (threadIdx.x == 0) {
        float deg = red[0] + 1.0f + (diagv ? diagv[i] : 0.0f);
        dis[i] = deg > 0.f ? 1.0f / sqrtf(deg) : 0.f;
    }
}

__global__ void k_pnorm(const float* __restrict__ p, float* __restrict__ nrm) {
    float v = p[threadIdx.x];
    float s = v * v;
    #pragma unroll
    for (int o = 32; o > 0; o >>= 1) s += __shfl_down(s, o);
    if (threadIdx.x == 0) nrm[0] = sqrtf(s);
}

__global__ void k_scores(const float* __restrict__ x, const float* __restrict__ pv,
                         const float* __restrict__ nrm, float* __restrict__ sc, int n) {
    __shared__ float pl[64];
    if (threadIdx.x < 64) pl[threadIdx.x] = pv[threadIdx.x];
    __syncthreads();
    int i = blockIdx.x * blockDim.x + threadIdx.x;
    if (i >= n) return;
    const float* xr = x + (size_t)i * 64;
    float d = 0.f;
    #pragma unroll
    for (int k = 0; k < 64; ++k) d += xr[k] * pl[k];
    sc[i] = tanhf(d / nrm[0]);
}

// full bitonic sort by (score desc, idx asc) == jax.lax.top_k stable semantics
template<int SZ>
__global__ void k_sort_topk(const float* __restrict__ score, int n, int k, int kp,
                            int* __restrict__ perm, float* __restrict__ scout) {
    __shared__ float s[SZ];
    __shared__ int id[SZ];
    for (int i = threadIdx.x; i < SZ; i += blockDim.x) {
        bool v = (i < n);
        s[i] = v ? score[i] : -INFINITY;
        id[i] = v ? i : 0x7FFFFFFF;
    }
    __syncthreads();
    for (int size = 2; size <= SZ; size <<= 1) {
        for (int stride = size >> 1; stride > 0; stride >>= 1) {
            for (int t = threadIdx.x; t < SZ / 2; t += blockDim.x) {
                int i = 2 * t - (t & (stride - 1));
                int j = i + stride;
                float si = s[i], sj = s[j];
                int ii = id[i], ij = id[j];
                bool before = (si > sj) || (si == sj && ii < ij);
                bool up = ((i & size) == 0);
                if (before != up) { s[i] = sj; s[j] = si; id[i] = ij; id[j] = ii; }
            }
            __syncthreads();
        }
    }
    for (int r = threadIdx.x; r < kp; r += blockDim.x) {
        perm[r] = (r < k) ? id[r] : 0;
        scout[r] = (r < k) ? s[r] : 0.f;
    }
}

__global__ void k_pool_x(const float* __restrict__ x, const int* __restrict__ perm,
                         const float* __restrict__ sc, float* __restrict__ xo, int k) {
    int t = blockIdx.x * blockDim.x + threadIdx.x;
    if (t >= k * 64) return;
    int r = t >> 6;
    xo[t] = x[(size_t)perm[r] * 64 + (t & 63)] * sc[r];
}

__global__ void k_build_inv(const int* __restrict__ perm, int* __restrict__ inv, int k) {
    int t = blockIdx.x * blockDim.x + threadIdx.x;
    if (t < k) inv[perm[t]] = t;
}

__global__ void k_unpool_add(const float* __restrict__ res, const float* __restrict__ xc,
                             const int* __restrict__ inv, float* __restrict__ o, int n) {
    int t = blockIdx.x * blockDim.x + threadIdx.x;
    if (t >= n * 64) return;
    int r = inv[t >> 6];
    o[t] = res[t] + (r >= 0 ? xc[(size_t)r * 64 + (t & 63)] : 0.f);
}

// XW = x@W ; Y = dis*XW (f32) ; Yt planes = 3-way bf16 split of Y^T ([64 x np])
__global__ void k_xw(const float* __restrict__ x, const float* __restrict__ W,
                     const float* __restrict__ dis, int n, int np, int cin, int ldw, int nout,
                     float* __restrict__ Y, unsigned short* __restrict__ T0,
                     unsigned short* __restrict__ T1, unsigned short* __restrict__ T2) {
    int t = blockIdx.x * blockDim.x + threadIdx.x;
    if (t >= np * 64) return;
    int i = t >> 6, f = t & 63;
    float y = 0.f;
    if (i < n && f < nout) {
        float a = 0.f;
        for (int k = 0; k < cin; ++k) a += x[(size_t)i * cin + k] * W[(size_t)k * ldw + f];
        y = dis[i] * a;
    }
    Y[t] = y;
    unsigned short h0 = f2bf(y);
    float r1 = y - bf2f(h0);
    unsigned short h1 = f2bf(r1);
    float r2 = r1 - bf2f(h1);
    size_t ti = (size_t)f * np + i;
    T0[ti] = h0; T1[ti] = h1; T2[ti] = f2bf(r2);
}

// ---------------- MFMA GEMMs ----------------
// LDS tile layout: row-major rows of 64 bf16 (128B), 8x16B chunks, chunk slot = c ^ (row&7).

// pooled augment: C = (A1[perm,:]) @ (A1[:,perm]); both operands as row-gathers
// (Q side gathers rows of the TRANSPOSED plane). PA/PB parts, all PA*PB products (exact).
template<int PA, int PB>
__global__ __launch_bounds__(256) void k_aug_gemm(
    const unsigned short* __restrict__ Pa, const unsigned short* __restrict__ Pb,
    const unsigned short* __restrict__ Qa, const unsigned short* __restrict__ Qb,
    const int* __restrict__ perm, int M, int N, int Kp, int ns, float* __restrict__ C)
{
    __shared__ __align__(16) unsigned short lp[PA * 8192];
    __shared__ __align__(16) unsigned short lq[PB * 8192];
    const int tid = threadIdx.x, lane = tid & 63;
    const int wm = tid >> 7, wn = (tid >> 6) & 1;
    const int bm = blockIdx.x * 128, bn = blockIdx.y * 128;
    const unsigned short* P[2] = {Pa, Pb};
    const unsigned short* Q[2] = {Qa, Qb};
    f32x4 acc[4][4] = {};
    const int l15 = lane & 15, kb = lane >> 4;
    for (int k0 = 0; k0 < Kp; k0 += 64) {
        __syncthreads();
        #pragma unroll
        for (int p = 0; p < PA; ++p)
            for (int s = tid; s < 1024; s += 256) {
                int row = s >> 3, sl = s & 7, c = sl ^ (row & 7);
                *(s16x8*)&lp[p * 8192 + s * 8] =
                    *(const s16x8*)(P[p] + (size_t)perm[bm + row] * ns + k0 + 8 * c);
            }
        #pragma unroll
        for (int p = 0; p < PB; ++p)
            for (int s = tid; s < 1024; s += 256) {
                int row = s >> 3, sl = s & 7, c = sl ^ (row & 7);
                *(s16x8*)&lq[p * 8192 + s * 8] =
                    *(const s16x8*)(Q[p] + (size_t)perm[bn + row] * ns + k0 + 8 * c);
            }
        __syncthreads();
        #pragma unroll
        for (int h = 0; h < 2; ++h) {
            s16x8 av[PA][4], bv[PB][4];
            #pragma unroll
            for (int p = 0; p < PA; ++p)
                #pragma unroll
                for (int mi = 0; mi < 4; ++mi) {
                    int row = wm * 64 + mi * 16 + l15;
                    int slot = (h * 4 + kb) ^ (row & 7);
                    av[p][mi] = *(const s16x8*)&lp[p * 8192 + row * 64 + slot * 8];
                }
            #pragma unroll
            for (int p = 0; p < PB; ++p)
                #pragma unroll
                for (int ni = 0; ni < 4; ++ni) {
                    int row = wn * 64 + ni * 16 + l15;
                    int slot = (h * 4 + kb) ^ (row & 7);
                    bv[p][ni] = *(const s16x8*)&lq[p * 8192 + row * 64 + slot * 8];
                }
            #pragma unroll
            for (int mi = 0; mi < 4; ++mi)
                #pragma unroll
                for (int ni = 0; ni < 4; ++ni)
                    #pragma unroll
                    for (int pa = 0; pa < PA; ++pa)
                        #pragma unroll
                        for (int pb = 0; pb < PB; ++pb)
                            acc[mi][ni] = __builtin_amdgcn_mfma_f32_16x16x32_bf16(
                                av[pa][mi], bv[pb][ni], acc[mi][ni], 0, 0, 0);
        }
    }
    const int l4 = lane >> 4;
    for (int mi = 0; mi < 4; ++mi)
        for (int ni = 0; ni < 4; ++ni)
            #pragma unroll
            for (int r = 0; r < 4; ++r) {
                int row = bm + wm * 64 + mi * 16 + l4 * 4 + r;
                int col = bn + wn * 64 + ni * 16 + l15;
                if (row < M && col < N)
                    C[(size_t)row * N + col] = (row == col) ? 0.f : acc[mi][ni][r];
            }
}

// gcn Z-partials: Z = Aplane @ Y, A int planes (PA parts), Y 3 parts, products pa+pb<=2.
// tile 64 x 64, 4 waves of 16 rows, K-split via blockIdx.y.
template<int PA>
__global__ __launch_bounds__(256) void k_gcn_gemm(
    const unsigned short* __restrict__ Aa, const unsigned short* __restrict__ Ab,
    const unsigned short* __restrict__ Ac,
    const unsigned short* __restrict__ B0, const unsigned short* __restrict__ B1,
    const unsigned short* __restrict__ B2,
    int np, int kchunk, float* __restrict__ Zp)
{
    __shared__ __align__(16) unsigned short la[PA * 4096];
    __shared__ __align__(16) unsigned short lb[3 * 4096];
    const int tid = threadIdx.x, lane = tid & 63, wv = tid >> 6;
    const int bm = blockIdx.x * 64;
    const int kbeg = blockIdx.y * kchunk;
    const unsigned short* A[3] = {Aa, Ab, Ac};
    const unsigned short* B[3] = {B0, B1, B2};
    f32x4 acc[4] = {};
    const int l15 = lane & 15, kb = lane >> 4;
    for (int kk = 0; kk < kchunk; kk += 64) {
        int k0 = kbeg + kk;
        __syncthreads();
        #pragma unroll
        for (int p = 0; p < PA; ++p)
            for (int s = tid; s < 512; s += 256) {
                int row = s >> 3, sl = s & 7, c = sl ^ (row & 7);
                *(s16x8*)&la[p * 4096 + s * 8] =
                    *(const s16x8*)(A[p] + (size_t)(bm + row) * np + k0 + 8 * c);
            }
        #pragma unroll
        for (int p = 0; p < 3; ++p)
            for (int s = tid; s < 512; s += 256) {
                int row = s >> 3, sl = s & 7, c = sl ^ (row & 7);
                *(s16x8*)&lb[p * 4096 + s * 8] =
                    *(const s16x8*)(B[p] + (size_t)row * np + k0 + 8 * c);
            }
        __syncthreads();
        #pragma unroll
        for (int h = 0; h < 2; ++h) {
            s16x8 av[PA], bv[3][4];
            #pragma unroll
            for (int p = 0; p < PA; ++p) {
                int row = wv * 16 + l15;
                int slot = (h * 4 + kb) ^ (row & 7);
                av[p] = *(const s16x8*)&la[p * 4096 + row * 64 + slot * 8];
            }
            #pragma unroll
            for (int p = 0; p < 3; ++p)
                #pragma unroll
                for (int ni = 0; ni < 4; ++ni) {
                    int row = ni * 16 + l15;
                    int slot = (h * 4 + kb) ^ (row & 7);
                    bv[p][ni] = *(const s16x8*)&lb[p * 4096 + row * 64 + slot * 8];
                }
            #pragma unroll
            for (int ni = 0; ni < 4; ++ni)
                #pragma unroll
                for (int pa = 0; pa < PA; ++pa)
                    #pragma unroll
                    for (int pb = 0; pb <= 2 - pa; ++pb)
                        acc[ni] = __builtin_amdgcn_mfma_f32_16x16x32_bf16(
                            av[pa], bv[pb][ni], acc[ni], 0, 0, 0);
        }
    }
    const int l4 = lane >> 4;
    float* Z = Zp + (size_t)blockIdx.y * np * 64;
    for (int ni = 0; ni < 4; ++ni)
        #pragma unroll
        for (int r = 0; r < 4; ++r) {
            int row = bm + wv * 16 + l4 * 4 + r;
            Z[(size_t)row * 64 + ni * 16 + l15] = acc[ni][r];
        }
}

// out = relu?( dis_i * (sum_ksplit Z + (diag_true+1)*Y_i) + b )
__global__ void k_gcn_epi(const float* __restrict__ Zp, const float* __restrict__ Y,
                          const float* __restrict__ dis, const float* __restrict__ diagv,
                          const float* __restrict__ b, int n, int np, int nout, int relu,
                          float* __restrict__ xo) {
    int t = blockIdx.x * blockDim.x + threadIdx.x;
    if (t >= n * 64) return;
    int i = t >> 6, f = t & 63;
    float s = 0.f;
    for (int kq = 0; kq < 8; ++kq) s += Zp[(size_t)kq * np * 64 + t];
    float coef = 1.f + (diagv ? diagv[i] : 0.f);
    float v = dis[i] * (s + coef * Y[t]) + (f < nout ? b[f] : 0.f);
    if (relu) v = fmaxf(v, 0.f);
    xo[t] = v;
}

template<int NP>
__global__ void k_split(const float* __restrict__ C, int kk, int kp,
                        unsigned short* __restrict__ H0, unsigned short* __restrict__ H1,
                        unsigned short* __restrict__ H2) {
    size_t t = (size_t)blockIdx.x * blockDim.x + threadIdx.x;
    if (t >= (size_t)kp * kp) return;
    int r = (int)(t / kp), c = (int)(t % kp);
    float v = (r < kk && c < kk) ? ((r == c) ? 1.f : C[(size_t)r * kk + c]) : 0.f;
    unsigned short h0 = f2bf(v);
    H0[t] = h0;
    if (NP > 1) {
        float r1 = v - bf2f(h0);
        unsigned short h1 = f2bf(r1);
        H1[t] = h1;
        if (NP > 2) H2[t] = f2bf(r1 - bf2f(h1));
    }
}

__global__ void k_softmax(const float* __restrict__ lg, float* __restrict__ o, int n) {
    int i = blockIdx.x * blockDim.x + threadIdx.x;
    if (i >= n) return;
    float a = lg[i * 64], b = lg[i * 64 + 1], c = lg[i * 64 + 2];
    float m = fmaxf(a, fmaxf(b, c));
    float ea = expf(a - m), eb = expf(b - m), ec = expf(c - m);
    float s = ea + eb + ec;
    o[i * 3] = ea / s; o[i * 3 + 1] = eb / s; o[i * 3 + 2] = ec / s;
}

// ---------------- launch ----------------

extern "C" void kernel_launch(void* const* d_in, const int* in_sizes, int n_in,
                              void* d_out, int out_size, void* d_ws, size_t ws_size,
                              hipStream_t stream) {
    const int N0 = 3072;
    const int E = in_sizes[1] / 2;
    const int CIN = in_sizes[0] / N0;   // 16

    const float* x_in = (const float*)d_in[0];
    const int*   eidx = (const int*)d_in[1];
    const float* Wd0 = (const float*)d_in[2];  const float* bd0 = (const float*)d_in[3];
    const float* Wd1 = (const float*)d_in[4];  const float* bd1 = (const float*)d_in[5];
    const float* Wd2 = (const float*)d_in[6];  const float* bd2 = (const float*)d_in[7];
    const float* Wd3 = (const float*)d_in[8];  const float* bd3 = (const float*)d_in[9];
    const float* p1  = (const float*)d_in[10]; const float* p2  = (const float*)d_in[11];
    const float* p3  = (const float*)d_in[12];
    const float* Wu0 = (const float*)d_in[13]; const float* bu0 = (const float*)d_in[14];
    const float* Wu1 = (const float*)d_in[15]; const float* bu1 = (const float*)d_in[16];
    const float* Wu2 = (const float*)d_in[17]; const float* bu2 = (const float*)d_in[18];
    float* out = (float*)d_out;

    char* ws = (char*)d_ws;
    size_t off = 0;
    auto alloc = [&](size_t bytes) -> void* {
        off = (off + 255) & ~(size_t)255;
        void* p = ws + off;
        off += bytes;
        return p;
    };

    unsigned short* A0H  = (unsigned short*)alloc((size_t)3072 * 3072 * 2);
    unsigned short* A0T  = (unsigned short*)alloc((size_t)3072 * 3072 * 2);
    float* d0   = (float*)alloc(3072 * 4);
    float* dis0 = (float*)alloc(3072 * 4);
    float* x0   = (float*)alloc((size_t)3072 * 64 * 4);
    unsigned short* P1H = (unsigned short*)alloc((size_t)2048 * 2048 * 2);
    unsigned short* P1T = (unsigned short*)alloc((size_t)2048 * 2048 * 2);
    float* dis1 = (float*)alloc(2048 * 4);
    float* x1   = (float*)alloc((size_t)2048 * 64 * 4);
    float* xp1  = (float*)alloc((size_t)2048 * 64 * 4);
    unsigned short* P2H  = (unsigned short*)alloc((size_t)1024 * 1024 * 2);
    unsigned short* P2L  = (unsigned short*)alloc((size_t)1024 * 1024 * 2);
    unsigned short* P2TH = (unsigned short*)alloc((size_t)1024 * 1024 * 2);
    unsigned short* P2TL = (unsigned short*)alloc((size_t)1024 * 1024 * 2);
    float* dis2 = (float*)alloc(1024 * 4);
    float* x2   = (float*)alloc((size_t)1024 * 64 * 4);
    float* xp2  = (float*)alloc((size_t)1024 * 64 * 4);
    unsigned short* P3a = (unsigned short*)alloc((size_t)512 * 512 * 2);
    unsigned short* P3b = (unsigned short*)alloc((size_t)512 * 512 * 2);
    unsigned short* P3c = (unsigned short*)alloc((size_t)512 * 512 * 2);
    float* dis3 = (float*)alloc(512 * 4);
    float* x3   = (float*)alloc((size_t)512 * 64 * 4);
    float* xp3  = (float*)alloc((size_t)512 * 64 * 4);
    int*   perm1 = (int*)alloc(2048 * 4);  float* sc1 = (float*)alloc(2048 * 4);
    int*   perm2 = (int*)alloc(1024 * 4);  float* sc2 = (float*)alloc(1024 * 4);
    int*   perm3 = (int*)alloc(512 * 4);   float* sc3 = (float*)alloc(512 * 4);
    float* score = (float*)alloc(3072 * 4);
    float* pnrm  = (float*)alloc(256);
    int*   inv   = (int*)alloc(3072 * 4);
    float* Yf  = (float*)alloc((size_t)3072 * 64 * 4);
    unsigned short* Yt0 = (unsigned short*)alloc((size_t)64 * 3072 * 2);
    unsigned short* Yt1 = (unsigned short*)alloc((size_t)64 * 3072 * 2);
    unsigned short* Yt2 = (unsigned short*)alloc((size_t)64 * 3072 * 2);
    float* Zp   = (float*)alloc((size_t)8 * 3072 * 64 * 4);
    float* xlog = (float*)alloc((size_t)3072 * 64 * 4);
    float* t2b  = (float*)alloc((size_t)1024 * 64 * 4);
    float* t1b  = (float*)alloc((size_t)2048 * 64 * 4);
    float* t0b  = (float*)alloc((size_t)3072 * 64 * 4);
    char* scratch = (char*)alloc((size_t)3072 * 3072 * 4);  // A0f / C1 / C2 / C3
    if (off > ws_size) return;  // workspace too small -> visible validation failure

    float* A0f = (float*)scratch;
    float* C1  = (float*)scratch;  // 2000x2000
    float* C2  = (float*)scratch;  // 1000x1000
    float* C3  = (float*)scratch;  // 500x500

    auto gcn = [&](const float* xin, int cin, const float* W, int ldw, int nout, const float* bias,
                   const unsigned short* Pa, const unsigned short* Pb2, const unsigned short* Pc,
                   int PA, int n, int np2, const float* dis, const float* diagv, int relu, float* xout) {
        k_xw<<<DIVUP(np2 * 64, 256), 256, 0, stream>>>(xin, W, dis, n, np2, cin, ldw, nout, Yf, Yt0, Yt1, Yt2);
        dim3 gg(np2 / 64, 8);
        int kch = np2 / 8;
        if (PA == 1)      k_gcn_gemm<1><<<gg, 256, 0, stream>>>(Pa, Pa, Pa, Yt0, Yt1, Yt2, np2, kch, Zp);
        else if (PA == 2) k_gcn_gemm<2><<<gg, 256, 0, stream>>>(Pa, Pb2, Pb2, Yt0, Yt1, Yt2, np2, kch, Zp);
        else              k_gcn_gemm<3><<<gg, 256, 0, stream>>>(Pa, Pb2, Pc, Yt0, Yt1, Yt2, np2, kch, Zp);
        k_gcn_epi<<<DIVUP(n * 64, 256), 256, 0, stream>>>(Zp, Yf, dis, diagv, bias, n, np2, nout, relu, xout);
    };

    // ---- build A0, planes, dis0 ----
    hipMemsetAsync(A0f, 0, (size_t)3072 * 3072 * 4, stream);
    k_scatter<<<DIVUP(E, 256), 256, 0, stream>>>(eidx, A0f, E, N0);
    k_a0_plane<<<DIVUP(3072 * 3072, 256), 256, 0, stream>>>(A0f, A0H, d0, N0);
    k_transpose_bf<<<dim3(96, 96), dim3(32, 8), 0, stream>>>(A0H, A0T, 3072);
    k_dis<<<3072, 256, 0, stream>>>(A0H, A0H, A0H, 1, d0, dis0, 3072);

    // ---- gcn0 ----
    gcn(x_in, CIN, Wd0, 64, 64, bd0, A0H, A0H, A0H, 1, 3072, 3072, dis0, d0, 1, x0);

    // ---- level 1: pool to 2000 ----
    k_pnorm<<<1, 64, 0, stream>>>(p1, pnrm);
    k_scores<<<DIVUP(3072, 256), 256, 0, stream>>>(x0, p1, pnrm, score, 3072);
    k_sort_topk<4096><<<1, 1024, 0, stream>>>(score, 3072, 2000, 2048, perm1, sc1);
    k_pool_x<<<DIVUP(2000 * 64, 256), 256, 0, stream>>>(x0, perm1, sc1, xp1, 2000);
    k_aug_gemm<1, 1><<<dim3(16, 16), 256, 0, stream>>>(A0H, A0H, A0T, A0T, perm1, 2000, 2000, 3072, 3072, C1);
    k_split<1><<<DIVUP(2048 * 2048, 256), 256, 0, stream>>>(C1, 2000, 2048, P1H, P1H, P1H);
    k_transpose_bf<<<dim3(64, 64), dim3(32, 8), 0, stream>>>(P1H, P1T, 2048);
    k_dis<<<2000, 256, 0, stream>>>(P1H, P1H, P1H, 1, nullptr, dis1, 2048);
    gcn(xp1, 64, Wd1, 64, 64, bd1, P1H, P1H, P1H, 1, 2000, 2048, dis1, nullptr, 1, x1);

    // ---- level 2: pool to 1000 ----
    k_pnorm<<<1, 64, 0, stream>>>(p2, pnrm);
    k_scores<<<DIVUP(2000, 256), 256, 0, stream>>>(x1, p2, pnrm, score, 2000);
    k_sort_topk<2048><<<1, 1024, 0, stream>>>(score, 2000, 1000, 1024, perm2, sc2);
    k_pool_x<<<DIVUP(1000 * 64, 256), 256, 0, stream>>>(x1, perm2, sc2, xp2, 1000);
    k_aug_gemm<1, 1><<<dim3(8, 8), 256, 0, stream>>>(P1H, P1H, P1T, P1T, perm2, 1000, 1000, 2048, 2048, C2);
    k_split<2><<<DIVUP(1024 * 1024, 256), 256, 0, stream>>>(C2, 1000, 1024, P2H, P2L, P2L);
    k_transpose_bf<<<dim3(32, 32), dim3(32, 8), 0, stream>>>(P2H, P2TH, 1024);
    k_transpose_bf<<<dim3(32, 32), dim3(32, 8), 0, stream>>>(P2L, P2TL, 1024);
    k_dis<<<1000, 256, 0, stream>>>(P2H, P2L, P2L, 2, nullptr, dis2, 1024);
    gcn(xp2, 64, Wd2, 64, 64, bd2, P2H, P2L, P2L, 2, 1000, 1024, dis2, nullptr, 1, x2);

    // ---- level 3: pool to 500 ----
    k_pnorm<<<1, 64, 0, stream>>>(p3, pnrm);
    k_scores<<<DIVUP(1000, 256), 256, 0, stream>>>(x2, p3, pnrm, score, 1000);
    k_sort_topk<1024><<<1, 1024, 0, stream>>>(score, 1000, 500, 512, perm3, sc3);
    k_pool_x<<<DIVUP(500 * 64, 256), 256, 0, stream>>>(x2, perm3, sc3, xp3, 500);
    k_aug_gemm<2, 2><<<dim3(4, 4), 256, 0, stream>>>(P2H, P2L, P2TH, P2TL, perm3, 500, 500, 1024, 1024, C3);
    k_split<3><<<DIVUP(512 * 512, 256), 256, 0, stream>>>(C3, 500, 512, P3a, P3b, P3c);
    k_dis<<<500, 256, 0, stream>>>(P3a, P3b, P3c, 3, nullptr, dis3, 512);
    gcn(xp3, 64, Wd3, 64, 64, bd3, P3a, P3b, P3c, 3, 500, 512, dis3, nullptr, 1, x3);

    // ---- up 0 (j=2): res=x2, A=P2, perm=perm3 ----
    hipMemsetAsync(inv, 0xFF, 1000 * 4, stream);
    k_build_inv<<<DIVUP(500, 256), 256, 0, stream>>>(perm3, inv, 500);
    k_unpool_add<<<DIVUP(1000 * 64, 256), 256, 0, stream>>>(x2, x3, inv, t2b, 1000);
    gcn(t2b, 64, Wu0, 64, 64, bu0, P2H, P2L, P2L, 2, 1000, 1024, dis2, nullptr, 1, xp2);  // xp2 = up-x (1000x64)

    // ---- up 1 (j=1): res=x1, A=P1, perm=perm2 ----
    hipMemsetAsync(inv, 0xFF, 2000 * 4, stream);
    k_build_inv<<<DIVUP(1000, 256), 256, 0, stream>>>(perm2, inv, 1000);
    k_unpool_add<<<DIVUP(2000 * 64, 256), 256, 0, stream>>>(x1, xp2, inv, t1b, 2000);
    gcn(t1b, 64, Wu1, 64, 64, bu1, P1H, P1H, P1H, 1, 2000, 2048, dis1, nullptr, 1, xp1);  // xp1 = up-x (2000x64)

    // ---- up 2 (j=0): res=x0, A=A0, perm=perm1, no relu, nout=3 ----
    hipMemsetAsync(inv, 0xFF, 3072 * 4, stream);
    k_build_inv<<<DIVUP(2000, 256), 256, 0, stream>>>(perm1, inv, 2000);
    k_unpool_add<<<DIVUP(3072 * 64, 256), 256, 0, stream>>>(x0, xp1, inv, t0b, 3072);
    gcn(t0b, 64, Wu2, 3, 3, bu2, A0H, A0H, A0H, 1, 3072, 3072, dis0, d0, 0, xlog);

    k_softmax<<<DIVUP(3072, 256), 256, 0, stream>>>(xlog, out, 3072);
}

// Round 2
// 524.851 us; speedup vs baseline: 1.6722x; 1.6722x over previous
//
#include <hip/hip_runtime.h>
#include <hip/hip_bf16.h>
#include <cstdint>
#include <cstddef>
#include <math.h>

// GraphUNet forward on MI355X.
// Integer adjacencies computed exactly via bf16-MFMA (split planes),
// GCN matmuls via 3-way-split bf16 MFMA (fp32-faithful), fused augment+pool,
// deterministic reductions (fp atomics only on exact-integer values),
// single-block bitonic top-k (stable ties), global_load_lds staging.

#define DIVUP(a,b) (((a)+(b)-1)/(b))

using s16x8 = __attribute__((ext_vector_type(8))) short;
using f32x4 = __attribute__((ext_vector_type(4))) float;

__device__ __forceinline__ unsigned short f2bf(float v) {
    union { float f; unsigned u; } a; a.f = v;
    unsigned u = a.u;
    u = u + 0x7FFFu + ((u >> 16) & 1u);   // RNE
    return (unsigned short)(u >> 16);
}
__device__ __forceinline__ float bf2f(unsigned short h) {
    union { unsigned u; float f; } a; a.u = ((unsigned)h) << 16; return a.f;
}
__device__ __forceinline__ void gload_lds16(const unsigned short* g, unsigned short* l) {
    __builtin_amdgcn_global_load_lds(
        (const __attribute__((address_space(1))) void*)g,
        (__attribute__((address_space(3))) void*)l, 16, 0, 0);
}

// ---------------- small kernels ----------------

__global__ void k_scatter(const int* __restrict__ e, float* __restrict__ A, int E, int n) {
    int t = blockIdx.x * blockDim.x + threadIdx.x;
    if (t < E) atomicAdd(&A[(size_t)e[t] * n + e[E + t]], 1.0f);  // integer adds: deterministic
}

__global__ void k_a0_plane(const float* __restrict__ A, unsigned short* __restrict__ H,
                           float* __restrict__ d0, int n) {
    size_t t = (size_t)blockIdx.x * blockDim.x + threadIdx.x;
    if (t >= (size_t)n * n) return;
    int i = (int)(t / n), j = (int)(t % n);
    float v = A[t];
    if (i == j) { d0[i] = v; v = 1.0f; }   // planes store diag=1 (augment-ready)
    H[t] = f2bf(v);
}

__global__ void k_transpose_bf(const unsigned short* __restrict__ S, unsigned short* __restrict__ D, int n) {
    __shared__ unsigned short tile[32][33];
    int bx = blockIdx.x * 32, by = blockIdx.y * 32;
    #pragma unroll
    for (int dy = 0; dy < 32; dy += 8)
        tile[threadIdx.y + dy][threadIdx.x] = S[(size_t)(by + threadIdx.y + dy) * n + bx + threadIdx.x];
    __syncthreads();
    #pragma unroll
    for (int dy = 0; dy < 32; dy += 8)
        D[(size_t)(bx + threadIdx.y + dy) * n + by + threadIdx.x] = tile[threadIdx.x][threadIdx.y + dy];
}

// deg_i = rowsum(plane parts) - 1 (stored diag) + diag_true + 2 ; dis = rsqrt
__global__ void k_dis(const unsigned short* __restrict__ P0, const unsigned short* __restrict__ P1,
                      const unsigned short* __restrict__ P2, int nplanes,
                      const float* __restrict__ diagv, float* __restrict__ dis, int np) {
    int i = blockIdx.x;
    float s = 0.f;
    const unsigned short* pls[3] = {P0, P1, P2};
    for (int p = 0; p < nplanes; ++p) {
        const unsigned short* row = pls[p] + (size_t)i * np;
        for (int j = threadIdx.x; j < np; j += 256) s += bf2f(row[j]);
    }
    __shared__ float red[256];
    red[threadIdx.x] = s; __syncthreads();
    for (int o = 128; o > 0; o >>= 1) {
        if (threadIdx.x < o) red[threadIdx.x] += red[threadIdx.x + o];
        __syncthreads();
    }
    if (threadIdx.x == 0) {
        float deg = red[0] + 1.0f + (diagv ? diagv[i] : 0.0f);
        dis[i] = deg > 0.f ? 1.0f / sqrtf(deg) : 0.f;
    }
}

__global__ void k_pnorm(const float* __restrict__ p, float* __restrict__ nrm) {
    float v = p[threadIdx.x];
    float s = v * v;
    #pragma unroll
    for (int o = 32; o > 0; o >>= 1) s += __shfl_down(s, o);
    if (threadIdx.x == 0) nrm[0] = sqrtf(s);
}

__global__ void k_scores(const float* __restrict__ x, const float* __restrict__ pv,
                         const float* __restrict__ nrm, float* __restrict__ sc, int n) {
    __shared__ float pl[64];
    if (threadIdx.x < 64) pl[threadIdx.x] = pv[threadIdx.x];
    __syncthreads();
    int i = blockIdx.x * blockDim.x + threadIdx.x;
    if (i >= n) return;
    const float* xr = x + (size_t)i * 64;
    float d = 0.f;
    #pragma unroll
    for (int k = 0; k < 64; ++k) d += xr[k] * pl[k];
    sc[i] = tanhf(d / nrm[0]);
}

// full bitonic sort by (score desc, idx asc) == jax.lax.top_k stable semantics
template<int SZ>
__global__ void k_sort_topk(const float* __restrict__ score, int n, int k, int kp,
                            int* __restrict__ perm, float* __restrict__ scout) {
    __shared__ float s[SZ];
    __shared__ int id[SZ];
    for (int i = threadIdx.x; i < SZ; i += blockDim.x) {
        bool v = (i < n);
        s[i] = v ? score[i] : -INFINITY;
        id[i] = v ? i : 0x7FFFFFFF;
    }
    __syncthreads();
    for (int size = 2; size <= SZ; size <<= 1) {
        for (int stride = size >> 1; stride > 0; stride >>= 1) {
            for (int t = threadIdx.x; t < SZ / 2; t += blockDim.x) {
                int i = 2 * t - (t & (stride - 1));
                int j = i + stride;
                float si = s[i], sj = s[j];
                int ii = id[i], ij = id[j];
                bool before = (si > sj) || (si == sj && ii < ij);
                bool up = ((i & size) == 0);
                if (before != up) { s[i] = sj; s[j] = si; id[i] = ij; id[j] = ii; }
            }
            __syncthreads();
        }
    }
    for (int r = threadIdx.x; r < kp; r += blockDim.x) {
        perm[r] = (r < k) ? id[r] : 0;
        scout[r] = (r < k) ? s[r] : 0.f;
    }
}

__global__ void k_pool_x(const float* __restrict__ x, const int* __restrict__ perm,
                         const float* __restrict__ sc, float* __restrict__ xo, int k) {
    int t = blockIdx.x * blockDim.x + threadIdx.x;
    if (t >= k * 64) return;
    int r = t >> 6;
    xo[t] = x[(size_t)perm[r] * 64 + (t & 63)] * sc[r];
}

__global__ void k_build_inv(const int* __restrict__ perm, int* __restrict__ inv, int k) {
    int t = blockIdx.x * blockDim.x + threadIdx.x;
    if (t < k) inv[perm[t]] = t;
}

__global__ void k_unpool_add(const float* __restrict__ res, const float* __restrict__ xc,
                             const int* __restrict__ inv, float* __restrict__ o, int n) {
    int t = blockIdx.x * blockDim.x + threadIdx.x;
    if (t >= n * 64) return;
    int r = inv[t >> 6];
    o[t] = res[t] + (r >= 0 ? xc[(size_t)r * 64 + (t & 63)] : 0.f);
}

// XW = x@W ; Y = dis*XW (f32) ; Yt planes = 3-way bf16 split of Y^T ([64 x np])
__global__ void k_xw(const float* __restrict__ x, const float* __restrict__ W,
                     const float* __restrict__ dis, int n, int np, int cin, int ldw, int nout,
                     float* __restrict__ Y, unsigned short* __restrict__ T0,
                     unsigned short* __restrict__ T1, unsigned short* __restrict__ T2) {
    int t = blockIdx.x * blockDim.x + threadIdx.x;
    if (t >= np * 64) return;
    int i = t >> 6, f = t & 63;
    float y = 0.f;
    if (i < n && f < nout) {
        float a = 0.f;
        for (int k = 0; k < cin; ++k) a += x[(size_t)i * cin + k] * W[(size_t)k * ldw + f];
        y = dis[i] * a;
    }
    Y[t] = y;
    unsigned short h0 = f2bf(y);
    float r1 = y - bf2f(h0);
    unsigned short h1 = f2bf(r1);
    float r2 = r1 - bf2f(h1);
    size_t ti = (size_t)f * np + i;
    T0[ti] = h0; T1[ti] = h1; T2[ti] = f2bf(r2);
}

// ---------------- MFMA GEMMs ----------------
// LDS tile: rows of 64 bf16 (128B) in 8x16B chunks; linear LDS dest, source
// chunk pre-swizzled c = slot ^ (row&7); reads use the same XOR (rule 21).

// pooled augment: C = (A1[perm,:]) @ (A1[:,perm]); Q side gathers rows of the
// TRANSPOSED plane. PA/PB parts, all PA*PB products (exact integers).
// K-split over blockIdx.z. ATOMIC=1: zero-skip atomicAdd (integer-exact,
// order-independent -> deterministic). ATOMIC=0: per-z partial buffers.
template<int PA, int PB, int ATOMIC>
__global__ __launch_bounds__(256) void k_aug_gemm(
    const unsigned short* __restrict__ Pa, const unsigned short* __restrict__ Pb,
    const unsigned short* __restrict__ Qa, const unsigned short* __restrict__ Qb,
    const int* __restrict__ perm, int M, int N, int kchunk, int ns, float* __restrict__ C)
{
    __shared__ __align__(16) unsigned short lp[PA * 8192];
    __shared__ __align__(16) unsigned short lq[PB * 8192];
    const int tid = threadIdx.x, lane = tid & 63;
    const int wm = tid >> 7, wn = (tid >> 6) & 1;
    const int bm = blockIdx.x * 128, bn = blockIdx.y * 128;
    const int kbeg = blockIdx.z * kchunk;
    const unsigned short* P[2] = {Pa, Pb};
    const unsigned short* Q[2] = {Qa, Qb};
    f32x4 acc[4][4] = {};
    const int l15 = lane & 15, kb = lane >> 4;
    for (int kk = 0; kk < kchunk; kk += 64) {
        int k0 = kbeg + kk;
        __syncthreads();
        #pragma unroll
        for (int p = 0; p < PA; ++p)
            for (int s = tid; s < 1024; s += 256) {
                int row = s >> 3, c = (s & 7) ^ (row & 7);
                gload_lds16(P[p] + (size_t)perm[bm + row] * ns + k0 + 8 * c,
                            &lp[p * 8192 + (s - lane) * 8]);
            }
        #pragma unroll
        for (int p = 0; p < PB; ++p)
            for (int s = tid; s < 1024; s += 256) {
                int row = s >> 3, c = (s & 7) ^ (row & 7);
                gload_lds16(Q[p] + (size_t)perm[bn + row] * ns + k0 + 8 * c,
                            &lq[p * 8192 + (s - lane) * 8]);
            }
        __syncthreads();
        #pragma unroll
        for (int h = 0; h < 2; ++h) {
            s16x8 av[PA][4], bv[PB][4];
            #pragma unroll
            for (int p = 0; p < PA; ++p)
                #pragma unroll
                for (int mi = 0; mi < 4; ++mi) {
                    int row = wm * 64 + mi * 16 + l15;
                    int slot = (h * 4 + kb) ^ (row & 7);
                    av[p][mi] = *(const s16x8*)&lp[p * 8192 + row * 64 + slot * 8];
                }
            #pragma unroll
            for (int p = 0; p < PB; ++p)
                #pragma unroll
                for (int ni = 0; ni < 4; ++ni) {
                    int row = wn * 64 + ni * 16 + l15;
                    int slot = (h * 4 + kb) ^ (row & 7);
                    bv[p][ni] = *(const s16x8*)&lq[p * 8192 + row * 64 + slot * 8];
                }
            #pragma unroll
            for (int mi = 0; mi < 4; ++mi)
                #pragma unroll
                for (int ni = 0; ni < 4; ++ni)
                    #pragma unroll
                    for (int pa = 0; pa < PA; ++pa)
                        #pragma unroll
                        for (int pb = 0; pb < PB; ++pb)
                            acc[mi][ni] = __builtin_amdgcn_mfma_f32_16x16x32_bf16(
                                av[pa][mi], bv[pb][ni], acc[mi][ni], 0, 0, 0);
        }
    }
    const int l4 = lane >> 4;
    float* Cb = ATOMIC ? C : (C + (size_t)blockIdx.z * M * N);
    for (int mi = 0; mi < 4; ++mi)
        for (int ni = 0; ni < 4; ++ni)
            #pragma unroll
            for (int r = 0; r < 4; ++r) {
                int row = bm + wm * 64 + mi * 16 + l4 * 4 + r;
                int col = bn + wn * 64 + ni * 16 + l15;
                if (row < M && col < N) {
                    float v = acc[mi][ni][r];
                    if (ATOMIC) { if (v != 0.f) atomicAdd(&Cb[(size_t)row * N + col], v); }
                    else Cb[(size_t)row * N + col] = v;
                }
            }
}

// gcn Z-partials: Z = Aplane @ Y, A int planes (PA parts), Y 3 parts, products
// pa+pb<=2. tile 64 x 64, 4 waves of 16 rows, K-split via blockIdx.y.
template<int PA>
__global__ __launch_bounds__(256) void k_gcn_gemm(
    const unsigned short* __restrict__ Aa, const unsigned short* __restrict__ Ab,
    const unsigned short* __restrict__ Ac,
    const unsigned short* __restrict__ B0, const unsigned short* __restrict__ B1,
    const unsigned short* __restrict__ B2,
    int np, int kchunk, float* __restrict__ Zp)
{
    __shared__ __align__(16) unsigned short la[PA * 4096];
    __shared__ __align__(16) unsigned short lb[3 * 4096];
    const int tid = threadIdx.x, lane = tid & 63, wv = tid >> 6;
    const int bm = blockIdx.x * 64;
    const int kbeg = blockIdx.y * kchunk;
    const unsigned short* A[3] = {Aa, Ab, Ac};
    const unsigned short* B[3] = {B0, B1, B2};
    f32x4 acc[4] = {};
    const int l15 = lane & 15, kb = lane >> 4;
    for (int kk = 0; kk < kchunk; kk += 64) {
        int k0 = kbeg + kk;
        __syncthreads();
        #pragma unroll
        for (int p = 0; p < PA; ++p)
            for (int s = tid; s < 512; s += 256) {
                int row = s >> 3, c = (s & 7) ^ (row & 7);
                gload_lds16(A[p] + (size_t)(bm + row) * np + k0 + 8 * c,
                            &la[p * 4096 + (s - lane) * 8]);
            }
        #pragma unroll
        for (int p = 0; p < 3; ++p)
            for (int s = tid; s < 512; s += 256) {
                int row = s >> 3, c = (s & 7) ^ (row & 7);
                gload_lds16(B[p] + (size_t)row * np + k0 + 8 * c,
                            &lb[p * 4096 + (s - lane) * 8]);
            }
        __syncthreads();
        #pragma unroll
        for (int h = 0; h < 2; ++h) {
            s16x8 av[PA], bv[3][4];
            #pragma unroll
            for (int p = 0; p < PA; ++p) {
                int row = wv * 16 + l15;
                int slot = (h * 4 + kb) ^ (row & 7);
                av[p] = *(const s16x8*)&la[p * 4096 + row * 64 + slot * 8];
            }
            #pragma unroll
            for (int p = 0; p < 3; ++p)
                #pragma unroll
                for (int ni = 0; ni < 4; ++ni) {
                    int row = ni * 16 + l15;
                    int slot = (h * 4 + kb) ^ (row & 7);
                    bv[p][ni] = *(const s16x8*)&lb[p * 4096 + row * 64 + slot * 8];
                }
            #pragma unroll
            for (int ni = 0; ni < 4; ++ni)
                #pragma unroll
                for (int pa = 0; pa < PA; ++pa)
                    #pragma unroll
                    for (int pb = 0; pb <= 2 - pa; ++pb)
                        acc[ni] = __builtin_amdgcn_mfma_f32_16x16x32_bf16(
                            av[pa], bv[pb][ni], acc[ni], 0, 0, 0);
        }
    }
    const int l4 = lane >> 4;
    float* Z = Zp + (size_t)blockIdx.y * np * 64;
    for (int ni = 0; ni < 4; ++ni)
        #pragma unroll
        for (int r = 0; r < 4; ++r) {
            int row = bm + wv * 16 + l4 * 4 + r;
            Z[(size_t)row * 64 + ni * 16 + l15] = acc[ni][r];
        }
}

// out = relu?( dis_i * (sum_ksplit Z + (diag_true+1)*Y_i) + b )
__global__ void k_gcn_epi(const float* __restrict__ Zp, const float* __restrict__ Y,
                          const float* __restrict__ dis, const float* __restrict__ diagv,
                          const float* __restrict__ b, int n, int np, int nout, int relu,
                          float* __restrict__ xo) {
    int t = blockIdx.x * blockDim.x + threadIdx.x;
    if (t >= n * 64) return;
    int i = t >> 6, f = t & 63;
    float s = 0.f;
    for (int kq = 0; kq < 8; ++kq) s += Zp[(size_t)kq * np * 64 + t];
    float coef = 1.f + (diagv ? diagv[i] : 0.f);
    float v = dis[i] * (s + coef * Y[t]) + (f < nout ? b[f] : 0.f);
    if (relu) v = fmaxf(v, 0.f);
    xo[t] = v;
}

// sum S K-split partials (stride pstr), force diag=1, split into NP bf16 planes
template<int NP>
__global__ void k_split(const float* __restrict__ C, int S, size_t pstr, int kk, int kp,
                        unsigned short* __restrict__ H0, unsigned short* __restrict__ H1,
                        unsigned short* __restrict__ H2) {
    size_t t = (size_t)blockIdx.x * blockDim.x + threadIdx.x;
    if (t >= (size_t)kp * kp) return;
    int r = (int)(t / kp), c = (int)(t % kp);
    float v = 0.f;
    if (r < kk && c < kk) {
        if (r == c) v = 1.f;
        else {
            for (int s = 0; s < S; ++s) v += C[(size_t)s * pstr + (size_t)r * kk + c];
        }
    }
    unsigned short h0 = f2bf(v);
    H0[t] = h0;
    if (NP > 1) {
        float r1 = v - bf2f(h0);
        unsigned short h1 = f2bf(r1);
        H1[t] = h1;
        if (NP > 2) H2[t] = f2bf(r1 - bf2f(h1));
    }
}

__global__ void k_softmax(const float* __restrict__ lg, float* __restrict__ o, int n) {
    int i = blockIdx.x * blockDim.x + threadIdx.x;
    if (i >= n) return;
    float a = lg[i * 64], b = lg[i * 64 + 1], c = lg[i * 64 + 2];
    float m = fmaxf(a, fmaxf(b, c));
    float ea = expf(a - m), eb = expf(b - m), ec = expf(c - m);
    float s = ea + eb + ec;
    o[i * 3] = ea / s; o[i * 3 + 1] = eb / s; o[i * 3 + 2] = ec / s;
}

// ---------------- launch ----------------

extern "C" void kernel_launch(void* const* d_in, const int* in_sizes, int n_in,
                              void* d_out, int out_size, void* d_ws, size_t ws_size,
                              hipStream_t stream) {
    const int N0 = 3072;
    const int E = in_sizes[1] / 2;
    const int CIN = in_sizes[0] / N0;   // 16

    const float* x_in = (const float*)d_in[0];
    const int*   eidx = (const int*)d_in[1];
    const float* Wd0 = (const float*)d_in[2];  const float* bd0 = (const float*)d_in[3];
    const float* Wd1 = (const float*)d_in[4];  const float* bd1 = (const float*)d_in[5];
    const float* Wd2 = (const float*)d_in[6];  const float* bd2 = (const float*)d_in[7];
    const float* Wd3 = (const float*)d_in[8];  const float* bd3 = (const float*)d_in[9];
    const float* p1  = (const float*)d_in[10]; const float* p2  = (const float*)d_in[11];
    const float* p3  = (const float*)d_in[12];
    const float* Wu0 = (const float*)d_in[13]; const float* bu0 = (const float*)d_in[14];
    const float* Wu1 = (const float*)d_in[15]; const float* bu1 = (const float*)d_in[16];
    const float* Wu2 = (const float*)d_in[17]; const float* bu2 = (const float*)d_in[18];
    float* out = (float*)d_out;

    char* ws = (char*)d_ws;
    size_t off = 0;
    auto alloc = [&](size_t bytes) -> void* {
        off = (off + 255) & ~(size_t)255;
        void* p = ws + off;
        off += bytes;
        return p;
    };

    unsigned short* A0H  = (unsigned short*)alloc((size_t)3072 * 3072 * 2);
    unsigned short* A0T  = (unsigned short*)alloc((size_t)3072 * 3072 * 2);
    float* d0   = (float*)alloc(3072 * 4);
    float* dis0 = (float*)alloc(3072 * 4);
    float* x0   = (float*)alloc((size_t)3072 * 64 * 4);
    unsigned short* P1H = (unsigned short*)alloc((size_t)2048 * 2048 * 2);
    unsigned short* P1T = (unsigned short*)alloc((size_t)2048 * 2048 * 2);
    float* dis1 = (float*)alloc(2048 * 4);
    float* x1   = (float*)alloc((size_t)2048 * 64 * 4);
    float* xp1  = (float*)alloc((size_t)2048 * 64 * 4);
    unsigned short* P2H  = (unsigned short*)alloc((size_t)1024 * 1024 * 2);
    unsigned short* P2L  = (unsigned short*)alloc((size_t)1024 * 1024 * 2);
    unsigned short* P2TH = (unsigned short*)alloc((size_t)1024 * 1024 * 2);
    unsigned short* P2TL = (unsigned short*)alloc((size_t)1024 * 1024 * 2);
    float* dis2 = (float*)alloc(1024 * 4);
    float* x2   = (float*)alloc((size_t)1024 * 64 * 4);
    float* xp2  = (float*)alloc((size_t)1024 * 64 * 4);
    unsigned short* P3a = (unsigned short*)alloc((size_t)512 * 512 * 2);
    unsigned short* P3b = (unsigned short*)alloc((size_t)512 * 512 * 2);
    unsigned short* P3c = (unsigned short*)alloc((size_t)512 * 512 * 2);
    float* dis3 = (float*)alloc(512 * 4);
    float* x3   = (float*)alloc((size_t)512 * 64 * 4);
    float* xp3  = (float*)alloc((size_t)512 * 64 * 4);
    int*   perm1 = (int*)alloc(2048 * 4);  float* sc1 = (float*)alloc(2048 * 4);
    int*   perm2 = (int*)alloc(1024 * 4);  float* sc2 = (float*)alloc(1024 * 4);
    int*   perm3 = (int*)alloc(512 * 4);   float* sc3 = (float*)alloc(512 * 4);
    float* score = (float*)alloc(3072 * 4);
    float* pnrm  = (float*)alloc(256);
    int*   inv   = (int*)alloc(3072 * 4);
    float* Yf  = (float*)alloc((size_t)3072 * 64 * 4);
    unsigned short* Yt0 = (unsigned short*)alloc((size_t)64 * 3072 * 2);
    unsigned short* Yt1 = (unsigned short*)alloc((size_t)64 * 3072 * 2);
    unsigned short* Yt2 = (unsigned short*)alloc((size_t)64 * 3072 * 2);
    float* Zp   = (float*)alloc((size_t)8 * 3072 * 64 * 4);
    float* xlog = (float*)alloc((size_t)3072 * 64 * 4);
    float* t2b  = (float*)alloc((size_t)1024 * 64 * 4);
    float* t1b  = (float*)alloc((size_t)2048 * 64 * 4);
    float* t0b  = (float*)alloc((size_t)3072 * 64 * 4);
    char* scratch = (char*)alloc((size_t)3072 * 3072 * 4);  // A0f / C1 / C2p / C3p
    if (off > ws_size) return;  // workspace too small -> visible validation failure

    float* A0f = (float*)scratch;
    float* C1  = (float*)scratch;  // 2000x2000 (atomic-accumulated)
    float* C2p = (float*)scratch;  // 8 x 1000x1000 partials (32 MB)
    float* C3p = (float*)scratch;  // 8 x 500x500 partials (8 MB)

    auto gcn = [&](const float* xin, int cin, const float* W, int ldw, int nout, const float* bias,
                   const unsigned short* Pa, const unsigned short* Pb2, const unsigned short* Pc,
                   int PA, int n, int np2, const float* dis, const float* diagv, int relu, float* xout) {
        k_xw<<<DIVUP(np2 * 64, 256), 256, 0, stream>>>(xin, W, dis, n, np2, cin, ldw, nout, Yf, Yt0, Yt1, Yt2);
        dim3 gg(np2 / 64, 8);
        int kch = np2 / 8;
        if (PA == 1)      k_gcn_gemm<1><<<gg, 256, 0, stream>>>(Pa, Pa, Pa, Yt0, Yt1, Yt2, np2, kch, Zp);
        else if (PA == 2) k_gcn_gemm<2><<<gg, 256, 0, stream>>>(Pa, Pb2, Pb2, Yt0, Yt1, Yt2, np2, kch, Zp);
        else              k_gcn_gemm<3><<<gg, 256, 0, stream>>>(Pa, Pb2, Pc, Yt0, Yt1, Yt2, np2, kch, Zp);
        k_gcn_epi<<<DIVUP(n * 64, 256), 256, 0, stream>>>(Zp, Yf, dis, diagv, bias, n, np2, nout, relu, xout);
    };

    // ---- build A0, planes, dis0 ----
    hipMemsetAsync(A0f, 0, (size_t)3072 * 3072 * 4, stream);
    k_scatter<<<DIVUP(E, 256), 256, 0, stream>>>(eidx, A0f, E, N0);
    k_a0_plane<<<DIVUP(3072 * 3072, 256), 256, 0, stream>>>(A0f, A0H, d0, N0);
    k_transpose_bf<<<dim3(96, 96), dim3(32, 8), 0, stream>>>(A0H, A0T, 3072);
    k_dis<<<3072, 256, 0, stream>>>(A0H, A0H, A0H, 1, d0, dis0, 3072);

    // ---- gcn0 ----
    gcn(x_in, CIN, Wd0, 64, 64, bd0, A0H, A0H, A0H, 1, 3072, 3072, dis0, d0, 1, x0);

    // ---- level 1: pool to 2000 ----
    k_pnorm<<<1, 64, 0, stream>>>(p1, pnrm);
    k_scores<<<DIVUP(3072, 256), 256, 0, stream>>>(x0, p1, pnrm, score, 3072);
    k_sort_topk<4096><<<1, 1024, 0, stream>>>(score, 3072, 2000, 2048, perm1, sc1);
    k_pool_x<<<DIVUP(2000 * 64, 256), 256, 0, stream>>>(x0, perm1, sc1, xp1, 2000);
    hipMemsetAsync(C1, 0, (size_t)2000 * 2000 * 4, stream);
    k_aug_gemm<1, 1, 1><<<dim3(16, 16, 8), 256, 0, stream>>>(A0H, A0H, A0T, A0T, perm1, 2000, 2000, 384, 3072, C1);
    k_split<1><<<DIVUP(2048 * 2048, 256), 256, 0, stream>>>(C1, 1, 0, 2000, 2048, P1H, P1H, P1H);
    k_transpose_bf<<<dim3(64, 64), dim3(32, 8), 0, stream>>>(P1H, P1T, 2048);
    k_dis<<<2000, 256, 0, stream>>>(P1H, P1H, P1H, 1, nullptr, dis1, 2048);
    gcn(xp1, 64, Wd1, 64, 64, bd1, P1H, P1H, P1H, 1, 2000, 2048, dis1, nullptr, 1, x1);

    // ---- level 2: pool to 1000 ----
    k_pnorm<<<1, 64, 0, stream>>>(p2, pnrm);
    k_scores<<<DIVUP(2000, 256), 256, 0, stream>>>(x1, p2, pnrm, score, 2000);
    k_sort_topk<2048><<<1, 1024, 0, stream>>>(score, 2000, 1000, 1024, perm2, sc2);
    k_pool_x<<<DIVUP(1000 * 64, 256), 256, 0, stream>>>(x1, perm2, sc2, xp2, 1000);
    k_aug_gemm<1, 1, 0><<<dim3(8, 8, 8), 256, 0, stream>>>(P1H, P1H, P1T, P1T, perm2, 1000, 1000, 256, 2048, C2p);
    k_split<2><<<DIVUP(1024 * 1024, 256), 256, 0, stream>>>(C2p, 8, (size_t)1000 * 1000, 1000, 1024, P2H, P2L, P2L);
    k_transpose_bf<<<dim3(32, 32), dim3(32, 8), 0, stream>>>(P2H, P2TH, 1024);
    k_transpose_bf<<<dim3(32, 32), dim3(32, 8), 0, stream>>>(P2L, P2TL, 1024);
    k_dis<<<1000, 256, 0, stream>>>(P2H, P2L, P2L, 2, nullptr, dis2, 1024);
    gcn(xp2, 64, Wd2, 64, 64, bd2, P2H, P2L, P2L, 2, 1000, 1024, dis2, nullptr, 1, x2);

    // ---- level 3: pool to 500 ----
    k_pnorm<<<1, 64, 0, stream>>>(p3, pnrm);
    k_scores<<<DIVUP(1000, 256), 256, 0, stream>>>(x2, p3, pnrm, score, 1000);
    k_sort_topk<1024><<<1, 1024, 0, stream>>>(score, 1000, 500, 512, perm3, sc3);
    k_pool_x<<<DIVUP(500 * 64, 256), 256, 0, stream>>>(x2, perm3, sc3, xp3, 500);
    k_aug_gemm<2, 2, 0><<<dim3(4, 4, 8), 256, 0, stream>>>(P2H, P2L, P2TH, P2TL, perm3, 500, 500, 128, 1024, C3p);
    k_split<3><<<DIVUP(512 * 512, 256), 256, 0, stream>>>(C3p, 8, (size_t)500 * 500, 500, 512, P3a, P3b, P3c);
    k_dis<<<500, 256, 0, stream>>>(P3a, P3b, P3c, 3, nullptr, dis3, 512);
    gcn(xp3, 64, Wd3, 64, 64, bd3, P3a, P3b, P3c, 3, 500, 512, dis3, nullptr, 1, x3);

    // ---- up 0 (j=2): res=x2, A=P2, perm=perm3 ----
    hipMemsetAsync(inv, 0xFF, 1000 * 4, stream);
    k_build_inv<<<DIVUP(500, 256), 256, 0, stream>>>(perm3, inv, 500);
    k_unpool_add<<<DIVUP(1000 * 64, 256), 256, 0, stream>>>(x2, x3, inv, t2b, 1000);
    gcn(t2b, 64, Wu0, 64, 64, bu0, P2H, P2L, P2L, 2, 1000, 1024, dis2, nullptr, 1, xp2);  // xp2 = up-x (1000x64)

    // ---- up 1 (j=1): res=x1, A=P1, perm=perm2 ----
    hipMemsetAsync(inv, 0xFF, 2000 * 4, stream);
    k_build_inv<<<DIVUP(1000, 256), 256, 0, stream>>>(perm2, inv, 1000);
    k_unpool_add<<<DIVUP(2000 * 64, 256), 256, 0, stream>>>(x1, xp2, inv, t1b, 2000);
    gcn(t1b, 64, Wu1, 64, 64, bu1, P1H, P1H, P1H, 1, 2000, 2048, dis1, nullptr, 1, xp1);  // xp1 = up-x (2000x64)

    // ---- up 2 (j=0): res=x0, A=A0, perm=perm1, no relu, nout=3 ----
    hipMemsetAsync(inv, 0xFF, 3072 * 4, stream);
    k_build_inv<<<DIVUP(2000, 256), 256, 0, stream>>>(perm1, inv, 2000);
    k_unpool_add<<<DIVUP(3072 * 64, 256), 256, 0, stream>>>(x0, xp1, inv, t0b, 3072);
    gcn(t0b, 64, Wu2, 3, 3, bu2, A0H, A0H, A0H, 1, 3072, 3072, dis0, d0, 0, xlog);

    k_softmax<<<DIVUP(3072, 256), 256, 0, stream>>>(xlog, out, 3072);
}

// Round 3
// 501.176 us; speedup vs baseline: 1.7511x; 1.0472x over previous
//
#include <hip/hip_runtime.h>
#include <hip/hip_bf16.h>
#include <cstdint>
#include <cstddef>
#include <math.h>

// GraphUNet forward on MI355X.
// Integer adjacencies computed exactly via bf16-MFMA (split planes),
// GCN matmuls via 3-way-split bf16 MFMA (fp32-faithful), fused augment+pool,
// deterministic reductions (fp atomics only on exact-integer values),
// single-block bitonic top-k (stable ties), global_load_lds staging,
// double-buffered LDS with hoisted row pointers (T3-minimum 2-phase pipeline).

#define DIVUP(a,b) (((a)+(b)-1)/(b))

using s16x8 = __attribute__((ext_vector_type(8))) short;
using f32x4 = __attribute__((ext_vector_type(4))) float;

__device__ __forceinline__ unsigned short f2bf(float v) {
    union { float f; unsigned u; } a; a.f = v;
    unsigned u = a.u;
    u = u + 0x7FFFu + ((u >> 16) & 1u);   // RNE
    return (unsigned short)(u >> 16);
}
__device__ __forceinline__ float bf2f(unsigned short h) {
    union { unsigned u; float f; } a; a.u = ((unsigned)h) << 16; return a.f;
}
__device__ __forceinline__ void gload_lds16(const unsigned short* g, unsigned short* l) {
    __builtin_amdgcn_global_load_lds(
        (const __attribute__((address_space(1))) void*)g,
        (__attribute__((address_space(3))) void*)l, 16, 0, 0);
}

// ---------------- small kernels ----------------

__global__ void k_scatter(const int* __restrict__ e, float* __restrict__ A, int E, int n) {
    int t = blockIdx.x * blockDim.x + threadIdx.x;
    if (t < E) atomicAdd(&A[(size_t)e[t] * n + e[E + t]], 1.0f);  // integer adds: deterministic
}

// plane (diag->1) + fused row-sum (block spans one row: 3072 % 256 == 0)
__global__ void k_a0_plane(const float* __restrict__ A, unsigned short* __restrict__ H,
                           float* __restrict__ d0, float* __restrict__ dsum, int n) {
    int t = blockIdx.x * 256 + threadIdx.x;
    int i = t / n, j = t - i * n;
    float v = A[t];
    if (i == j) { d0[i] = v; v = 1.0f; }
    H[t] = f2bf(v);
    __shared__ float red[256];
    red[threadIdx.x] = v; __syncthreads();
    for (int o = 128; o > 0; o >>= 1) {
        if (threadIdx.x < o) red[threadIdx.x] += red[threadIdx.x + o];
        __syncthreads();
    }
    if (threadIdx.x == 0) atomicAdd(&dsum[i], red[0]);  // integer-exact
}

__global__ void k_transpose_bf(const unsigned short* __restrict__ S, unsigned short* __restrict__ D, int n) {
    __shared__ unsigned short tile[32][33];
    int bx = blockIdx.x * 32, by = blockIdx.y * 32;
    #pragma unroll
    for (int dy = 0; dy < 32; dy += 8)
        tile[threadIdx.y + dy][threadIdx.x] = S[(size_t)(by + threadIdx.y + dy) * n + bx + threadIdx.x];
    __syncthreads();
    #pragma unroll
    for (int dy = 0; dy < 32; dy += 8)
        D[(size_t)(bx + threadIdx.y + dy) * n + by + threadIdx.x] = tile[threadIdx.x][threadIdx.y + dy];
}

// dis = 1/sqrt(dsum + 1 + diag)
__global__ void k_disv(const float* __restrict__ dsum, const float* __restrict__ diag,
                       float* __restrict__ dis, int n) {
    int i = blockIdx.x * blockDim.x + threadIdx.x;
    if (i >= n) return;
    float deg = dsum[i] + 1.0f + (diag ? diag[i] : 0.0f);
    dis[i] = deg > 0.f ? 1.0f / sqrtf(deg) : 0.f;
}

// scores with fused pnorm (redundant per block, 64 FLOP)
__global__ void k_scores(const float* __restrict__ x, const float* __restrict__ pv,
                         float* __restrict__ sc, int n) {
    __shared__ float pl[64];
    if (threadIdx.x < 64) pl[threadIdx.x] = pv[threadIdx.x];
    __syncthreads();
    float n2 = 0.f;
    #pragma unroll
    for (int k = 0; k < 64; ++k) n2 += pl[k] * pl[k];
    float nrm = sqrtf(n2);
    int i = blockIdx.x * blockDim.x + threadIdx.x;
    if (i >= n) return;
    const float* xr = x + (size_t)i * 64;
    float d = 0.f;
    #pragma unroll
    for (int k = 0; k < 64; ++k) d += xr[k] * pl[k];
    sc[i] = tanhf(d / nrm);
}

// full bitonic sort by (score desc, idx asc) == jax.lax.top_k stable semantics
template<int SZ>
__global__ void k_sort_topk(const float* __restrict__ score, int n, int k, int kp,
                            int* __restrict__ perm, float* __restrict__ scout) {
    __shared__ float s[SZ];
    __shared__ int id[SZ];
    for (int i = threadIdx.x; i < SZ; i += blockDim.x) {
        bool v = (i < n);
        s[i] = v ? score[i] : -INFINITY;
        id[i] = v ? i : 0x7FFFFFFF;
    }
    __syncthreads();
    for (int size = 2; size <= SZ; size <<= 1) {
        for (int stride = size >> 1; stride > 0; stride >>= 1) {
            for (int t = threadIdx.x; t < SZ / 2; t += blockDim.x) {
                int i = 2 * t - (t & (stride - 1));
                int j = i + stride;
                float si = s[i], sj = s[j];
                int ii = id[i], ij = id[j];
                bool before = (si > sj) || (si == sj && ii < ij);
                bool up = ((i & size) == 0);
                if (before != up) { s[i] = sj; s[j] = si; id[i] = ij; id[j] = ii; }
            }
            __syncthreads();
        }
    }
    for (int r = threadIdx.x; r < kp; r += blockDim.x) {
        perm[r] = (r < k) ? id[r] : 0;
        scout[r] = (r < k) ? s[r] : 0.f;
    }
}

__global__ void k_pool_x(const float* __restrict__ x, const int* __restrict__ perm,
                         const float* __restrict__ sc, float* __restrict__ xo, int k) {
    int t = blockIdx.x * blockDim.x + threadIdx.x;
    if (t >= k * 64) return;
    int r = t >> 6;
    xo[t] = x[(size_t)perm[r] * 64 + (t & 63)] * sc[r];
}

__global__ void k_build_inv(const int* __restrict__ perm, int* __restrict__ inv, int k) {
    int t = blockIdx.x * blockDim.x + threadIdx.x;
    if (t < k) inv[perm[t]] = t;
}

__global__ void k_unpool_add(const float* __restrict__ res, const float* __restrict__ xc,
                             const int* __restrict__ inv, float* __restrict__ o, int n) {
    int t = blockIdx.x * blockDim.x + threadIdx.x;
    if (t >= n * 64) return;
    int r = inv[t >> 6];
    o[t] = res[t] + (r >= 0 ? xc[(size_t)r * 64 + (t & 63)] : 0.f);
}

// XW = x@W ; Y = dis*XW (f32) ; Yt planes = 3-way bf16 split of Y^T ([64 x np])
__global__ void k_xw(const float* __restrict__ x, const float* __restrict__ W,
                     const float* __restrict__ dis, int n, int np, int cin, int ldw, int nout,
                     float* __restrict__ Y, unsigned short* __restrict__ T0,
                     unsigned short* __restrict__ T1, unsigned short* __restrict__ T2) {
    int t = blockIdx.x * blockDim.x + threadIdx.x;
    if (t >= np * 64) return;
    int i = t >> 6, f = t & 63;
    float y = 0.f;
    if (i < n && f < nout) {
        float a = 0.f;
        for (int k = 0; k < cin; ++k) a += x[(size_t)i * cin + k] * W[(size_t)k * ldw + f];
        y = dis[i] * a;
    }
    Y[t] = y;
    unsigned short h0 = f2bf(y);
    float r1 = y - bf2f(h0);
    unsigned short h1 = f2bf(r1);
    float r2 = r1 - bf2f(h1);
    size_t ti = (size_t)f * np + i;
    T0[ti] = h0; T1[ti] = h1; T2[ti] = f2bf(r2);
}

// ---------------- MFMA GEMMs ----------------
// LDS tile: rows of 64 bf16 (128B) in 8x16B chunks; linear LDS dest, source
// chunk pre-swizzled c = slot ^ (row&7); reads use the same XOR (rule 21).
// Row pointers hoisted out of the K-loop; DBUF=1: stage(next) -> compute(cur)
// -> one __syncthreads per K-tile (its vmcnt(0) drain is the recipe's wait).

template<int PA, int PB, int ATOMIC, int DBUF>
__global__ __launch_bounds__(256) void k_aug_gemm(
    const unsigned short* __restrict__ Pa, const unsigned short* __restrict__ Pb,
    const unsigned short* __restrict__ Qa, const unsigned short* __restrict__ Qb,
    const int* __restrict__ perm, int M, int N, int kchunk, int ns, float* __restrict__ C)
{
    __shared__ __align__(16) unsigned short lp[DBUF + 1][PA * 8192];
    __shared__ __align__(16) unsigned short lq[DBUF + 1][PB * 8192];
    const int tid = threadIdx.x, lane = tid & 63;
    const int wm = tid >> 7, wn = (tid >> 6) & 1;
    const int bm = blockIdx.x * 128, bn = blockIdx.y * 128;
    const int kbeg = blockIdx.z * kchunk;
    const unsigned short* P[2] = {Pa, Pb};
    const unsigned short* Q[2] = {Qa, Qb};
    const unsigned short* sp[PA][4];
    const unsigned short* sq[PB][4];
    int dst[4];
    #pragma unroll
    for (int it = 0; it < 4; ++it) {
        int s = tid + it * 256;
        int row = s >> 3, c = (s & 7) ^ (row & 7);
        dst[it] = (s - lane) * 8;
        #pragma unroll
        for (int p = 0; p < PA; ++p)
            sp[p][it] = P[p] + (size_t)perm[bm + row] * ns + kbeg + 8 * c;
        #pragma unroll
        for (int p = 0; p < PB; ++p)
            sq[p][it] = Q[p] + (size_t)perm[bn + row] * ns + kbeg + 8 * c;
    }
    f32x4 acc[4][4] = {};
    const int l15 = lane & 15, kb = lane >> 4;
    const int nt = kchunk >> 6;

    auto stage = [&](int b, int koff) {
        #pragma unroll
        for (int p = 0; p < PA; ++p)
            #pragma unroll
            for (int it = 0; it < 4; ++it)
                gload_lds16(sp[p][it] + koff, &lp[b][p * 8192 + dst[it]]);
        #pragma unroll
        for (int p = 0; p < PB; ++p)
            #pragma unroll
            for (int it = 0; it < 4; ++it)
                gload_lds16(sq[p][it] + koff, &lq[b][p * 8192 + dst[it]]);
    };
    auto compute = [&](int b) {
        #pragma unroll
        for (int h = 0; h < 2; ++h) {
            s16x8 av[PA][4], bv[PB][4];
            #pragma unroll
            for (int p = 0; p < PA; ++p)
                #pragma unroll
                for (int mi = 0; mi < 4; ++mi) {
                    int row = wm * 64 + mi * 16 + l15;
                    int slot = (h * 4 + kb) ^ (row & 7);
                    av[p][mi] = *(const s16x8*)&lp[b][p * 8192 + row * 64 + slot * 8];
                }
            #pragma unroll
            for (int p = 0; p < PB; ++p)
                #pragma unroll
                for (int ni = 0; ni < 4; ++ni) {
                    int row = wn * 64 + ni * 16 + l15;
                    int slot = (h * 4 + kb) ^ (row & 7);
                    bv[p][ni] = *(const s16x8*)&lq[b][p * 8192 + row * 64 + slot * 8];
                }
            #pragma unroll
            for (int mi = 0; mi < 4; ++mi)
                #pragma unroll
                for (int ni = 0; ni < 4; ++ni)
                    #pragma unroll
                    for (int pa = 0; pa < PA; ++pa)
                        #pragma unroll
                        for (int pb = 0; pb < PB; ++pb)
                            acc[mi][ni] = __builtin_amdgcn_mfma_f32_16x16x32_bf16(
                                av[pa][mi], bv[pb][ni], acc[mi][ni], 0, 0, 0);
        }
    };

    if (DBUF) {
        stage(0, 0);
        __syncthreads();
        for (int t = 0; t < nt; ++t) {
            if (t + 1 < nt) stage((t + 1) & 1, (t + 1) * 64);
            compute(t & 1);
            __syncthreads();
        }
    } else {
        for (int t = 0; t < nt; ++t) {
            if (t) __syncthreads();
            stage(0, t * 64);
            __syncthreads();
            compute(0);
        }
    }

    const int l4 = lane >> 4;
    float* Cb = ATOMIC ? C : (C + (size_t)blockIdx.z * M * N);
    for (int mi = 0; mi < 4; ++mi)
        for (int ni = 0; ni < 4; ++ni)
            #pragma unroll
            for (int r = 0; r < 4; ++r) {
                int row = bm + wm * 64 + mi * 16 + l4 * 4 + r;
                int col = bn + wn * 64 + ni * 16 + l15;
                if (row < M && col < N) {
                    float v = acc[mi][ni][r];
                    if (ATOMIC) { if (v != 0.f) atomicAdd(&Cb[(size_t)row * N + col], v); }
                    else Cb[(size_t)row * N + col] = v;
                }
            }
}

// gcn Z-partials: Z = Aplane @ Y, A int planes (PA parts), Y 3 parts, products
// pa+pb<=2. tile 64 x 64, 4 waves of 16 rows, K-split via blockIdx.y.
template<int PA, int DBUF>
__global__ __launch_bounds__(256) void k_gcn_gemm(
    const unsigned short* __restrict__ Aa, const unsigned short* __restrict__ Ab,
    const unsigned short* __restrict__ Ac,
    const unsigned short* __restrict__ B0, const unsigned short* __restrict__ B1,
    const unsigned short* __restrict__ B2,
    int np, int kchunk, float* __restrict__ Zp)
{
    __shared__ __align__(16) unsigned short la[DBUF + 1][PA * 4096];
    __shared__ __align__(16) unsigned short lb[DBUF + 1][3 * 4096];
    const int tid = threadIdx.x, lane = tid & 63, wv = tid >> 6;
    const int bm = blockIdx.x * 64;
    const int kbeg = blockIdx.y * kchunk;
    const unsigned short* A[3] = {Aa, Ab, Ac};
    const unsigned short* B[3] = {B0, B1, B2};
    const unsigned short* sa[PA][2];
    const unsigned short* sb[3][2];
    int dst[2];
    #pragma unroll
    for (int it = 0; it < 2; ++it) {
        int s = tid + it * 256;
        int row = s >> 3, c = (s & 7) ^ (row & 7);
        dst[it] = (s - lane) * 8;
        #pragma unroll
        for (int p = 0; p < PA; ++p)
            sa[p][it] = A[p] + (size_t)(bm + row) * np + kbeg + 8 * c;
        #pragma unroll
        for (int p = 0; p < 3; ++p)
            sb[p][it] = B[p] + (size_t)row * np + kbeg + 8 * c;
    }
    f32x4 acc[4] = {};
    const int l15 = lane & 15, kb = lane >> 4;
    const int nt = kchunk >> 6;

    auto stage = [&](int b, int koff) {
        #pragma unroll
        for (int p = 0; p < PA; ++p)
            #pragma unroll
            for (int it = 0; it < 2; ++it)
                gload_lds16(sa[p][it] + koff, &la[b][p * 4096 + dst[it]]);
        #pragma unroll
        for (int p = 0; p < 3; ++p)
            #pragma unroll
            for (int it = 0; it < 2; ++it)
                gload_lds16(sb[p][it] + koff, &lb[b][p * 4096 + dst[it]]);
    };
    auto compute = [&](int b) {
        #pragma unroll
        for (int h = 0; h < 2; ++h) {
            s16x8 av[PA], bv[3][4];
            #pragma unroll
            for (int p = 0; p < PA; ++p) {
                int row = wv * 16 + l15;
                int slot = (h * 4 + kb) ^ (row & 7);
                av[p] = *(const s16x8*)&la[b][p * 4096 + row * 64 + slot * 8];
            }
            #pragma unroll
            for (int p = 0; p < 3; ++p)
                #pragma unroll
                for (int ni = 0; ni < 4; ++ni) {
                    int row = ni * 16 + l15;
                    int slot = (h * 4 + kb) ^ (row & 7);
                    bv[p][ni] = *(const s16x8*)&lb[b][p * 4096 + row * 64 + slot * 8];
                }
            #pragma unroll
            for (int ni = 0; ni < 4; ++ni)
                #pragma unroll
                for (int pa = 0; pa < PA; ++pa)
                    #pragma unroll
                    for (int pb = 0; pb <= 2 - pa; ++pb)
                        acc[ni] = __builtin_amdgcn_mfma_f32_16x16x32_bf16(
                            av[pa], bv[pb][ni], acc[ni], 0, 0, 0);
        }
    };

    if (DBUF) {
        stage(0, 0);
        __syncthreads();
        for (int t = 0; t < nt; ++t) {
            if (t + 1 < nt) stage((t + 1) & 1, (t + 1) * 64);
            compute(t & 1);
            __syncthreads();
        }
    } else {
        for (int t = 0; t < nt; ++t) {
            if (t) __syncthreads();
            stage(0, t * 64);
            __syncthreads();
            compute(0);
        }
    }

    const int l4 = lane >> 4;
    float* Z = Zp + (size_t)blockIdx.y * np * 64;
    for (int ni = 0; ni < 4; ++ni)
        #pragma unroll
        for (int r = 0; r < 4; ++r) {
            int row = bm + wv * 16 + l4 * 4 + r;
            Z[(size_t)row * 64 + ni * 16 + l15] = acc[ni][r];
        }
}

// out = relu?( dis_i * (sum_ksplit Z + (diag_true+1)*Y_i) + b )
__global__ void k_gcn_epi(const float* __restrict__ Zp, const float* __restrict__ Y,
                          const float* __restrict__ dis, const float* __restrict__ diagv,
                          const float* __restrict__ b, int n, int np, int nout, int relu,
                          float* __restrict__ xo) {
    int t = blockIdx.x * blockDim.x + threadIdx.x;
    if (t >= n * 64) return;
    int i = t >> 6, f = t & 63;
    float s = 0.f;
    for (int kq = 0; kq < 8; ++kq) s += Zp[(size_t)kq * np * 64 + t];
    float coef = 1.f + (diagv ? diagv[i] : 0.f);
    float v = dis[i] * (s + coef * Y[t]) + (f < nout ? b[f] : 0.f);
    if (relu) v = fmaxf(v, 0.f);
    xo[t] = v;
}

// fused: sum S K-split partials, diag=1, split NP planes, write NT transposed
// planes, atomic per-row sums (integer-exact -> deterministic). 32x32 tiles.
template<int NP, int NT>
__global__ void k_split_t(const float* __restrict__ C, int S, size_t pstr, int kk, int kp,
                          unsigned short* __restrict__ H0, unsigned short* __restrict__ H1,
                          unsigned short* __restrict__ H2,
                          unsigned short* __restrict__ T0, unsigned short* __restrict__ T1,
                          float* __restrict__ dsum) {
    __shared__ unsigned short tl[NT ? NT : 1][32][33];
    const int tx = threadIdx.x & 31, ty = threadIdx.x >> 5;
    const int r0 = blockIdx.y * 32, c0 = blockIdx.x * 32;
    const int c = c0 + tx;
    #pragma unroll
    for (int dy = 0; dy < 4; ++dy) {
        int rt = ty + dy * 8;
        int r = r0 + rt;
        float v = 0.f;
        if (r < kk && c < kk) {
            if (r == c) v = 1.f;
            else for (int s = 0; s < S; ++s) v += C[(size_t)s * pstr + (size_t)r * kk + c];
        }
        unsigned short h0 = f2bf(v);
        size_t o = (size_t)r * kp + c;
        H0[o] = h0;
        if (NT > 0) tl[0][rt][tx] = h0;
        if (NP > 1) {
            float r1 = v - bf2f(h0);
            unsigned short h1 = f2bf(r1);
            H1[o] = h1;
            if (NT > 1) tl[1][rt][tx] = h1;
            if (NP > 2) H2[o] = f2bf(r1 - bf2f(h1));
        }
        float sum = v;
        #pragma unroll
        for (int o2 = 16; o2 > 0; o2 >>= 1) sum += __shfl_xor(sum, o2, 32);
        if (tx == 0) atomicAdd(&dsum[r], sum);
    }
    if (NT > 0) {
        __syncthreads();
        #pragma unroll
        for (int dy = 0; dy < 4; ++dy) {
            int rt = ty + dy * 8;
            size_t o = (size_t)(c0 + rt) * kp + r0 + tx;
            T0[o] = tl[0][tx][rt];
            if (NT > 1) T1[o] = tl[1][tx][rt];
        }
    }
}

__global__ void k_softmax(const float* __restrict__ lg, float* __restrict__ o, int n) {
    int i = blockIdx.x * blockDim.x + threadIdx.x;
    if (i >= n) return;
    float a = lg[i * 64], b = lg[i * 64 + 1], c = lg[i * 64 + 2];
    float m = fmaxf(a, fmaxf(b, c));
    float ea = expf(a - m), eb = expf(b - m), ec = expf(c - m);
    float s = ea + eb + ec;
    o[i * 3] = ea / s; o[i * 3 + 1] = eb / s; o[i * 3 + 2] = ec / s;
}

// ---------------- launch ----------------

extern "C" void kernel_launch(void* const* d_in, const int* in_sizes, int n_in,
                              void* d_out, int out_size, void* d_ws, size_t ws_size,
                              hipStream_t stream) {
    const int N0 = 3072;
    const int E = in_sizes[1] / 2;
    const int CIN = in_sizes[0] / N0;   // 16

    const float* x_in = (const float*)d_in[0];
    const int*   eidx = (const int*)d_in[1];
    const float* Wd0 = (const float*)d_in[2];  const float* bd0 = (const float*)d_in[3];
    const float* Wd1 = (const float*)d_in[4];  const float* bd1 = (const float*)d_in[5];
    const float* Wd2 = (const float*)d_in[6];  const float* bd2 = (const float*)d_in[7];
    const float* Wd3 = (const float*)d_in[8];  const float* bd3 = (const float*)d_in[9];
    const float* p1  = (const float*)d_in[10]; const float* p2  = (const float*)d_in[11];
    const float* p3  = (const float*)d_in[12];
    const float* Wu0 = (const float*)d_in[13]; const float* bu0 = (const float*)d_in[14];
    const float* Wu1 = (const float*)d_in[15]; const float* bu1 = (const float*)d_in[16];
    const float* Wu2 = (const float*)d_in[17]; const float* bu2 = (const float*)d_in[18];
    float* out = (float*)d_out;

    char* ws = (char*)d_ws;
    size_t off = 0;
    auto alloc = [&](size_t bytes) -> void* {
        off = (off + 255) & ~(size_t)255;
        void* p = ws + off;
        off += bytes;
        return p;
    };

    unsigned short* A0H  = (unsigned short*)alloc((size_t)3072 * 3072 * 2);
    unsigned short* A0T  = (unsigned short*)alloc((size_t)3072 * 3072 * 2);
    float* d0   = (float*)alloc(3072 * 4);
    float* dis0 = (float*)alloc(3072 * 4);
    float* x0   = (float*)alloc((size_t)3072 * 64 * 4);
    unsigned short* P1H = (unsigned short*)alloc((size_t)2048 * 2048 * 2);
    unsigned short* P1T = (unsigned short*)alloc((size_t)2048 * 2048 * 2);
    float* dis1 = (float*)alloc(2048 * 4);
    float* x1   = (float*)alloc((size_t)2048 * 64 * 4);
    float* xp1  = (float*)alloc((size_t)2048 * 64 * 4);
    unsigned short* P2H  = (unsigned short*)alloc((size_t)1024 * 1024 * 2);
    unsigned short* P2L  = (unsigned short*)alloc((size_t)1024 * 1024 * 2);
    unsigned short* P2TH = (unsigned short*)alloc((size_t)1024 * 1024 * 2);
    unsigned short* P2TL = (unsigned short*)alloc((size_t)1024 * 1024 * 2);
    float* dis2 = (float*)alloc(1024 * 4);
    float* x2   = (float*)alloc((size_t)1024 * 64 * 4);
    float* xp2  = (float*)alloc((size_t)1024 * 64 * 4);
    unsigned short* P3a = (unsigned short*)alloc((size_t)512 * 512 * 2);
    unsigned short* P3b = (unsigned short*)alloc((size_t)512 * 512 * 2);
    unsigned short* P3c = (unsigned short*)alloc((size_t)512 * 512 * 2);
    float* dis3 = (float*)alloc(512 * 4);
    float* x3   = (float*)alloc((size_t)512 * 64 * 4);
    float* xp3  = (float*)alloc((size_t)512 * 64 * 4);
    int*   perm1 = (int*)alloc(2048 * 4);  float* sc1 = (float*)alloc(2048 * 4);
    int*   perm2 = (int*)alloc(1024 * 4);  float* sc2 = (float*)alloc(1024 * 4);
    int*   perm3 = (int*)alloc(512 * 4);   float* sc3 = (float*)alloc(512 * 4);
    float* score = (float*)alloc(3072 * 4);
    // dsum0..3 contiguous (one memset); 256-aligned sizes keep them adjacent
    float* dsum0 = (float*)alloc(3072 * 4);
    float* dsum1 = (float*)alloc(2048 * 4);
    float* dsum2 = (float*)alloc(1024 * 4);
    float* dsum3 = (float*)alloc(512 * 4);
    // inv arrays contiguous (one memset)
    int* inv2 = (int*)alloc(1024 * 4);
    int* inv1 = (int*)alloc(2048 * 4);
    int* inv0 = (int*)alloc(3072 * 4);
    float* Yf  = (float*)alloc((size_t)3072 * 64 * 4);
    unsigned short* Yt0 = (unsigned short*)alloc((size_t)64 * 3072 * 2);
    unsigned short* Yt1 = (unsigned short*)alloc((size_t)64 * 3072 * 2);
    unsigned short* Yt2 = (unsigned short*)alloc((size_t)64 * 3072 * 2);
    float* Zp   = (float*)alloc((size_t)8 * 3072 * 64 * 4);
    float* xlog = (float*)alloc((size_t)3072 * 64 * 4);
    float* t2b  = (float*)alloc((size_t)1024 * 64 * 4);
    float* t1b  = (float*)alloc((size_t)2048 * 64 * 4);
    float* t0b  = (float*)alloc((size_t)3072 * 64 * 4);
    char* scratch = (char*)alloc((size_t)3072 * 3072 * 4);  // A0f / C1 / C2p / C3p
    if (off > ws_size) return;  // workspace too small -> visible validation failure

    float* A0f = (float*)scratch;
    float* C1  = (float*)scratch;  // 2000x2000 (atomic-accumulated)
    float* C2p = (float*)scratch;  // 8 x 1000x1000 partials (32 MB)
    float* C3p = (float*)scratch;  // 8 x 500x500 partials (8 MB)

    auto gcn = [&](const float* xin, int cin, const float* W, int ldw, int nout, const float* bias,
                   const unsigned short* Pa, const unsigned short* Pb2, const unsigned short* Pc,
                   int PA, int n, int np2, const float* dis, const float* diagv, int relu, float* xout) {
        k_xw<<<DIVUP(np2 * 64, 256), 256, 0, stream>>>(xin, W, dis, n, np2, cin, ldw, nout, Yf, Yt0, Yt1, Yt2);
        dim3 gg(np2 / 64, 8);
        int kch = np2 / 8;
        if (PA == 1)      k_gcn_gemm<1, 1><<<gg, 256, 0, stream>>>(Pa, Pa, Pa, Yt0, Yt1, Yt2, np2, kch, Zp);
        else if (PA == 2) k_gcn_gemm<2, 0><<<gg, 256, 0, stream>>>(Pa, Pb2, Pb2, Yt0, Yt1, Yt2, np2, kch, Zp);
        else              k_gcn_gemm<3, 0><<<gg, 256, 0, stream>>>(Pa, Pb2, Pc, Yt0, Yt1, Yt2, np2, kch, Zp);
        k_gcn_epi<<<DIVUP(n * 64, 256), 256, 0, stream>>>(Zp, Yf, dis, diagv, bias, n, np2, nout, relu, xout);
    };

    // ---- zero accumulators (inside graph -> re-zeroed each replay) ----
    hipMemsetAsync(dsum0, 0, (char*)(inv2) - (char*)dsum0, stream);
    hipMemsetAsync(inv2, 0xFF, (char*)(inv0 + 3072) - (char*)inv2, stream);

    // ---- build A0, planes, dis0 ----
    hipMemsetAsync(A0f, 0, (size_t)3072 * 3072 * 4, stream);
    k_scatter<<<DIVUP(E, 256), 256, 0, stream>>>(eidx, A0f, E, N0);
    k_a0_plane<<<3072 * 3072 / 256, 256, 0, stream>>>(A0f, A0H, d0, dsum0, N0);
    k_transpose_bf<<<dim3(96, 96), dim3(32, 8), 0, stream>>>(A0H, A0T, 3072);
    k_disv<<<DIVUP(3072, 256), 256, 0, stream>>>(dsum0, d0, dis0, 3072);

    // ---- gcn0 ----
    gcn(x_in, CIN, Wd0, 64, 64, bd0, A0H, A0H, A0H, 1, 3072, 3072, dis0, d0, 1, x0);

    // ---- level 1: pool to 2000 ----
    k_scores<<<DIVUP(3072, 256), 256, 0, stream>>>(x0, p1, score, 3072);
    k_sort_topk<4096><<<1, 1024, 0, stream>>>(score, 3072, 2000, 2048, perm1, sc1);
    k_pool_x<<<DIVUP(2000 * 64, 256), 256, 0, stream>>>(x0, perm1, sc1, xp1, 2000);
    hipMemsetAsync(C1, 0, (size_t)2000 * 2000 * 4, stream);
    k_aug_gemm<1, 1, 1, 1><<<dim3(16, 16, 8), 256, 0, stream>>>(A0H, A0H, A0T, A0T, perm1, 2000, 2000, 384, 3072, C1);
    k_split_t<1, 1><<<dim3(64, 64), 256, 0, stream>>>(C1, 1, 0, 2000, 2048, P1H, P1H, P1H, P1T, P1T, dsum1);
    k_disv<<<DIVUP(2048, 256), 256, 0, stream>>>(dsum1, nullptr, dis1, 2048);
    gcn(xp1, 64, Wd1, 64, 64, bd1, P1H, P1H, P1H, 1, 2000, 2048, dis1, nullptr, 1, x1);

    // ---- level 2: pool to 1000 ----
    k_scores<<<DIVUP(2000, 256), 256, 0, stream>>>(x1, p2, score, 2000);
    k_sort_topk<2048><<<1, 1024, 0, stream>>>(score, 2000, 1000, 1024, perm2, sc2);
    k_pool_x<<<DIVUP(1000 * 64, 256), 256, 0, stream>>>(x1, perm2, sc2, xp2, 1000);
    k_aug_gemm<1, 1, 0, 1><<<dim3(8, 8, 8), 256, 0, stream>>>(P1H, P1H, P1T, P1T, perm2, 1000, 1000, 256, 2048, C2p);
    k_split_t<2, 2><<<dim3(32, 32), 256, 0, stream>>>(C2p, 8, (size_t)1000 * 1000, 1000, 1024, P2H, P2L, P2L, P2TH, P2TL, dsum2);
    k_disv<<<DIVUP(1024, 256), 256, 0, stream>>>(dsum2, nullptr, dis2, 1024);
    gcn(xp2, 64, Wd2, 64, 64, bd2, P2H, P2L, P2L, 2, 1000, 1024, dis2, nullptr, 1, x2);

    // ---- level 3: pool to 500 ----
    k_scores<<<DIVUP(1000, 256), 256, 0, stream>>>(x2, p3, score, 1000);
    k_sort_topk<1024><<<1, 1024, 0, stream>>>(score, 1000, 500, 512, perm3, sc3);
    k_pool_x<<<DIVUP(500 * 64, 256), 256, 0, stream>>>(x2, perm3, sc3, xp3, 500);
    k_aug_gemm<2, 2, 0, 0><<<dim3(4, 4, 8), 256, 0, stream>>>(P2H, P2L, P2TH, P2TL, perm3, 500, 500, 128, 1024, C3p);
    k_split_t<3, 0><<<dim3(16, 16), 256, 0, stream>>>(C3p, 8, (size_t)500 * 500, 500, 512, P3a, P3b, P3c, nullptr, nullptr, dsum3);
    k_disv<<<DIVUP(512, 256), 256, 0, stream>>>(dsum3, nullptr, dis3, 512);
    gcn(xp3, 64, Wd3, 64, 64, bd3, P3a, P3b, P3c, 3, 500, 512, dis3, nullptr, 1, x3);

    // ---- up 0 (j=2): res=x2, A=P2, perm=perm3 ----
    k_build_inv<<<DIVUP(500, 256), 256, 0, stream>>>(perm3, inv2, 500);
    k_unpool_add<<<DIVUP(1000 * 64, 256), 256, 0, stream>>>(x2, x3, inv2, t2b, 1000);
    gcn(t2b, 64, Wu0, 64, 64, bu0, P2H, P2L, P2L, 2, 1000, 1024, dis2, nullptr, 1, xp2);  // xp2 = up-x (1000x64)

    // ---- up 1 (j=1): res=x1, A=P1, perm=perm2 ----
    k_build_inv<<<DIVUP(1000, 256), 256, 0, stream>>>(perm2, inv1, 1000);
    k_unpool_add<<<DIVUP(2000 * 64, 256), 256, 0, stream>>>(x1, xp2, inv1, t1b, 2000);
    gcn(t1b, 64, Wu1, 64, 64, bu1, P1H, P1H, P1H, 1, 2000, 2048, dis1, nullptr, 1, xp1);  // xp1 = up-x (2000x64)

    // ---- up 2 (j=0): res=x0, A=A0, perm=perm1, no relu, nout=3 ----
    k_build_inv<<<DIVUP(2000, 256), 256, 0, stream>>>(perm1, inv0, 2000);
    k_unpool_add<<<DIVUP(3072 * 64, 256), 256, 0, stream>>>(x0, xp1, inv0, t0b, 3072);
    gcn(t0b, 64, Wu2, 3, 3, bu2, A0H, A0H, A0H, 1, 3072, 3072, dis0, d0, 0, xlog);

    k_softmax<<<DIVUP(3072, 256), 256, 0, stream>>>(xlog, out, 3072);
}